// Round 1
// baseline (578.256 us; speedup 1.0000x reference)
//
#include <hip/hip_runtime.h>
#include <math.h>

#define N_ 50000
#define E_ 640000
#define H_ 128
#define L_ 3
#define G_ 256
#define C_ 10
#define NEG_SLOPE 0.2f

__device__ __forceinline__ float leaky(float x) { return x > 0.f ? x : NEG_SLOPE * x; }

// ---------------- utility ----------------
__global__ void zero_i32(int* __restrict__ p, int n) {
    int i = blockIdx.x * blockDim.x + threadIdx.x;
    if (i < n) p[i] = 0;
}

// ---------------- CSR build ----------------
__global__ void count_deg(const int* __restrict__ dst, int* __restrict__ cnt) {
    int i = blockIdx.x * blockDim.x + threadIdx.x;
    if (i < E_) atomicAdd(&cnt[dst[i]], 1);
}

__global__ __launch_bounds__(1024) void scan_deg(const int* __restrict__ cnt,
                                                 int* __restrict__ rowptr) {
    __shared__ int sdata[1024];
    __shared__ int carry;
    if (threadIdx.x == 0) carry = 0;
    __syncthreads();
    for (int base = 0; base < N_; base += 1024) {
        int i = base + threadIdx.x;
        int v = (i < N_) ? cnt[i] : 0;
        sdata[threadIdx.x] = v;
        __syncthreads();
        for (int off = 1; off < 1024; off <<= 1) {
            int t = (threadIdx.x >= off) ? sdata[threadIdx.x - off] : 0;
            __syncthreads();
            sdata[threadIdx.x] += t;
            __syncthreads();
        }
        if (i < N_) rowptr[i] = carry + sdata[threadIdx.x] - v;  // exclusive
        __syncthreads();
        if (threadIdx.x == 0) carry += sdata[1023];
        __syncthreads();
    }
    if (threadIdx.x == 0) rowptr[N_] = carry;
}

__global__ void fill_csr(const int* __restrict__ src, const int* __restrict__ dst,
                         const int* __restrict__ rowptr, int* __restrict__ cur,
                         int* __restrict__ col) {
    int i = blockIdx.x * blockDim.x + threadIdx.x;
    if (i < E_) {
        int d = dst[i];
        int p = atomicAdd(&cur[d], 1);
        col[rowptr[d] + p] = src[i];
    }
}

// ---------------- GEMM: Hout[n,128] = A[n,128] @ W[128,128] ----------------
__global__ __launch_bounds__(256) void gemm128(const float* __restrict__ A,
                                               const float* __restrict__ W,
                                               float* __restrict__ Hout, int nrows) {
    __shared__ float xt[128][32];  // transposed x tile: xt[k][r]
    int block_row = blockIdx.x * 32;
    int tid = threadIdx.x;
    {
        int r = tid >> 3;
        int k0 = (tid & 7) * 16;
        int grow = block_row + r;
        const float* srcp = A + (size_t)grow * 128 + k0;
#pragma unroll
        for (int q = 0; q < 4; q++) {
            float4 v = (grow < nrows) ? *(const float4*)(srcp + q * 4)
                                      : make_float4(0.f, 0.f, 0.f, 0.f);
            xt[k0 + q * 4 + 0][r] = v.x;
            xt[k0 + q * 4 + 1][r] = v.y;
            xt[k0 + q * 4 + 2][r] = v.z;
            xt[k0 + q * 4 + 3][r] = v.w;
        }
    }
    __syncthreads();
    int c0 = (tid & 31) * 4;
    int r0 = (tid >> 5) * 4;
    float acc[4][4] = {};
#pragma unroll 4
    for (int k = 0; k < 128; k++) {
        float4 xv = *(const float4*)&xt[k][r0];
        float4 wv = *(const float4*)(W + k * 128 + c0);
        acc[0][0] += xv.x * wv.x; acc[0][1] += xv.x * wv.y; acc[0][2] += xv.x * wv.z; acc[0][3] += xv.x * wv.w;
        acc[1][0] += xv.y * wv.x; acc[1][1] += xv.y * wv.y; acc[1][2] += xv.y * wv.z; acc[1][3] += xv.y * wv.w;
        acc[2][0] += xv.z * wv.x; acc[2][1] += xv.z * wv.y; acc[2][2] += xv.z * wv.z; acc[2][3] += xv.z * wv.w;
        acc[3][0] += xv.w * wv.x; acc[3][1] += xv.w * wv.y; acc[3][2] += xv.w * wv.z; acc[3][3] += xv.w * wv.w;
    }
#pragma unroll
    for (int r = 0; r < 4; r++) {
        int grow = block_row + r0 + r;
        if (grow < nrows) {
            *(float4*)(Hout + (size_t)grow * 128 + c0) =
                make_float4(acc[r][0], acc[r][1], acc[r][2], acc[r][3]);
        }
    }
}

// ---------------- attention logits per node ----------------
__global__ __launch_bounds__(256) void compute_es_ed(const float* __restrict__ h,
                                                     const float* __restrict__ a_s,
                                                     const float* __restrict__ a_d,
                                                     float* __restrict__ es,
                                                     float* __restrict__ ed) {
    int node = blockIdx.x * 4 + (threadIdx.x >> 6);
    int lane = threadIdx.x & 63;
    if (node >= N_) return;
    float h0 = h[(size_t)node * 128 + lane];
    float h1 = h[(size_t)node * 128 + 64 + lane];
    float s = h0 * a_s[lane] + h1 * a_s[64 + lane];
    float d = h0 * a_d[lane] + h1 * a_d[64 + lane];
#pragma unroll
    for (int o = 32; o; o >>= 1) {
        s += __shfl_xor(s, o);
        d += __shfl_xor(d, o);
    }
    if (lane == 0) {
        es[node] = s;
        ed[node] = d;
    }
}

// ---------------- edge-softmax + aggregate (one wave per dst node) ----------------
__global__ __launch_bounds__(256) void gat_aggregate(const float* __restrict__ h,
                                                     const float* __restrict__ es,
                                                     const float* __restrict__ ed,
                                                     const int* __restrict__ rowptr,
                                                     const int* __restrict__ col,
                                                     const float* __restrict__ bias,
                                                     float* __restrict__ hout) {
    int node = blockIdx.x * 4 + (threadIdx.x >> 6);
    int lane = threadIdx.x & 63;
    if (node >= N_) return;
    int beg = rowptr[node];
    int end = rowptr[node + 1];
    float edn = ed[node];
    float e_self = leaky(es[node] + edn);

    // pass 1: max (lane-parallel over edges)
    float m = e_self;
    for (int i = beg + lane; i < end; i += 64) m = fmaxf(m, leaky(es[col[i]] + edn));
#pragma unroll
    for (int o = 32; o; o >>= 1) m = fmaxf(m, __shfl_xor(m, o));

    // pass 2: denom
    float z = 0.f;
    for (int i = beg + lane; i < end; i += 64) z += expf(leaky(es[col[i]] + edn) - m);
#pragma unroll
    for (int o = 32; o; o >>= 1) z += __shfl_xor(z, o);
    z += expf(e_self - m);
    float inv = 1.0f / (z + 1e-16f);

    // pass 3: weighted aggregation (serial edges, lanes span 128 features)
    float w = expf(e_self - m);
    float a0 = w * h[(size_t)node * 128 + lane];
    float a1 = w * h[(size_t)node * 128 + 64 + lane];
    for (int i = beg; i < end; ++i) {
        int s = col[i];
        float wi = expf(leaky(es[s] + edn) - m);
        a0 += wi * h[(size_t)s * 128 + lane];
        a1 += wi * h[(size_t)s * 128 + 64 + lane];
    }
    hout[(size_t)node * 128 + lane]      = fmaxf(a0 * inv + bias[lane], 0.f);
    hout[(size_t)node * 128 + 64 + lane] = fmaxf(a1 * inv + bias[64 + lane], 0.f);
}

// ---------------- global max pool (batch sorted -> binary search bounds) ----------------
__device__ __forceinline__ int lower_bound_batch(const int* __restrict__ batch, int val) {
    int lo = 0, hi = N_;
    while (lo < hi) {
        int mid = (lo + hi) >> 1;
        if (batch[mid] < val) lo = mid + 1;
        else hi = mid;
    }
    return lo;
}

__global__ __launch_bounds__(512) void pool_max(const float* __restrict__ h,
                                                const int* __restrict__ batch,
                                                float* __restrict__ gpool) {
    int g = blockIdx.x;
    int s = lower_bound_batch(batch, g);
    int e = lower_bound_batch(batch, g + 1);
    int f = threadIdx.x & 127;
    int rg = threadIdx.x >> 7;  // 4 row groups
    float m = 0.f;  // h is post-ReLU (>=0), segments non-empty
    for (int i = s + rg; i < e; i += 4) m = fmaxf(m, h[(size_t)i * 128 + f]);
    __shared__ float red[4][128];
    red[rg][f] = m;
    __syncthreads();
    if (rg == 0) {
        m = fmaxf(fmaxf(red[0][f], red[1][f]), fmaxf(red[2][f], red[3][f]));
        gpool[g * 128 + f] = m;
    }
}

// ---------------- MLP head + log_softmax ----------------
__global__ __launch_bounds__(128) void head(const float* __restrict__ gpool,
                                            const float* __restrict__ W1,
                                            const float* __restrict__ b1,
                                            const float* __restrict__ W2,
                                            const float* __restrict__ b2,
                                            float* __restrict__ out) {
    int g = blockIdx.x;
    int t = threadIdx.x;
    __shared__ float gs[128], gp[128], lg[C_], lse;
    gs[t] = gpool[g * 128 + t];
    __syncthreads();
    float acc = b1[t];
#pragma unroll 8
    for (int k = 0; k < 128; k++) acc += gs[k] * W1[k * 128 + t];
    gp[t] = fmaxf(acc, 0.f);
    __syncthreads();
    if (t < C_) {
        float a2 = b2[t];
#pragma unroll 8
        for (int k = 0; k < 128; k++) a2 += gp[k] * W2[k * C_ + t];
        lg[t] = a2;
    }
    __syncthreads();
    if (t == 0) {
        float mm = lg[0];
#pragma unroll
        for (int i = 1; i < C_; i++) mm = fmaxf(mm, lg[i]);
        float ss = 0.f;
#pragma unroll
        for (int i = 0; i < C_; i++) ss += expf(lg[i] - mm);
        lse = mm + logf(ss);
    }
    __syncthreads();
    if (t < C_) out[g * C_ + t] = lg[t] - lse;
}

// ---------------- launch ----------------
extern "C" void kernel_launch(void* const* d_in, const int* in_sizes, int n_in,
                              void* d_out, int out_size, void* d_ws, size_t ws_size,
                              hipStream_t stream) {
    const float* x     = (const float*)d_in[0];
    const int*   eidx  = (const int*)d_in[1];
    const int*   batch = (const int*)d_in[2];
    const float* Wc    = (const float*)d_in[3];
    const float* a_src = (const float*)d_in[4];
    const float* a_dst = (const float*)d_in[5];
    const float* bc    = (const float*)d_in[6];
    const float* W1    = (const float*)d_in[7];
    const float* b1    = (const float*)d_in[8];
    const float* W2    = (const float*)d_in[9];
    const float* b2    = (const float*)d_in[10];
    float* out = (float*)d_out;

    const int* srcs = eidx;        // edge_index[0]
    const int* dsts = eidx + E_;   // edge_index[1]

    // workspace layout
    float* hA    = (float*)d_ws;          // N*128
    float* hB    = hA + (size_t)N_ * 128; // N*128
    float* es    = hB + (size_t)N_ * 128; // N
    float* ed    = es + N_;               // N
    float* gpool = ed + N_;               // G*128
    int* rowptr  = (int*)(gpool + G_ * 128); // N+1
    int* cnt     = rowptr + N_ + 1;          // N
    int* col     = cnt + N_;                 // E

    // ---- CSR build (once; reused by all layers) ----
    zero_i32<<<(N_ + 1023) / 1024, 1024, 0, stream>>>(cnt, N_);
    count_deg<<<(E_ + 255) / 256, 256, 0, stream>>>(dsts, cnt);
    scan_deg<<<1, 1024, 0, stream>>>(cnt, rowptr);
    zero_i32<<<(N_ + 1023) / 1024, 1024, 0, stream>>>(cnt, N_);
    fill_csr<<<(E_ + 255) / 256, 256, 0, stream>>>(srcs, dsts, rowptr, cnt, col);

    // ---- 3 GAT layers ----
    const float* h_in = x;
    for (int l = 0; l < L_; ++l) {
        const float* Wl = Wc + (size_t)l * H_ * H_;
        gemm128<<<(N_ + 31) / 32, 256, 0, stream>>>(h_in, Wl, hA, N_);
        compute_es_ed<<<(N_ + 3) / 4, 256, 0, stream>>>(hA, a_src + l * H_, a_dst + l * H_, es, ed);
        gat_aggregate<<<(N_ + 3) / 4, 256, 0, stream>>>(hA, es, ed, rowptr, col, bc + l * H_, hB);
        h_in = hB;  // hA is scratch again next layer
    }

    // ---- pool + head ----
    pool_max<<<G_, 512, 0, stream>>>(hB, batch, gpool);
    head<<<G_, 128, 0, stream>>>(gpool, W1, b1, W2, b2, out);
}

// Round 2
// 473.650 us; speedup vs baseline: 1.2208x; 1.2208x over previous
//
#include <hip/hip_runtime.h>
#include <math.h>

#define N_ 50000
#define E_ 640000
#define H_ 128
#define L_ 3
#define G_ 256
#define C_ 10
#define NEG_SLOPE 0.2f

#define SCAN_B 256
#define NBLK ((N_ + SCAN_B - 1) / SCAN_B)   // 196

__device__ __forceinline__ float leaky(float x) { return x > 0.f ? x : NEG_SLOPE * x; }

// ---------------- utility ----------------
__global__ void zero_i32(int* __restrict__ p, int n) {
    int i = blockIdx.x * blockDim.x + threadIdx.x;
    if (i < n) p[i] = 0;
}

// ---------------- CSR build ----------------
__global__ void count_deg(const int* __restrict__ dst, int* __restrict__ cnt) {
    int i = blockIdx.x * blockDim.x + threadIdx.x;
    if (i < E_) atomicAdd(&cnt[dst[i]], 1);
}

// two-level scan: (1) per-block wave-shuffle scan + block sums
__global__ __launch_bounds__(SCAN_B) void scan_block(const int* __restrict__ cnt,
                                                     int* __restrict__ rowptr,
                                                     int* __restrict__ bsums) {
    int tid = threadIdx.x;
    int gid = blockIdx.x * SCAN_B + tid;
    int v = (gid < N_) ? cnt[gid] : 0;
    int lane = tid & 63, wid = tid >> 6;
    int x = v;
#pragma unroll
    for (int o = 1; o < 64; o <<= 1) {
        int t = __shfl_up(x, o);
        if (lane >= o) x += t;
    }
    __shared__ int wsum[4];
    if (lane == 63) wsum[wid] = x;
    __syncthreads();
    int woff = 0;
    for (int i = 0; i < wid; i++) woff += wsum[i];
    int incl = x + woff;
    if (gid < N_) rowptr[gid] = incl - v;           // exclusive within block
    if (tid == SCAN_B - 1) bsums[blockIdx.x] = incl; // block total
}

// (2) scan the 196 block sums in-place -> exclusive offsets
__global__ __launch_bounds__(256) void scan_bsums(int* __restrict__ bsums, int nb) {
    int tid = threadIdx.x;
    int v = (tid < nb) ? bsums[tid] : 0;
    int lane = tid & 63, wid = tid >> 6;
    int x = v;
#pragma unroll
    for (int o = 1; o < 64; o <<= 1) {
        int t = __shfl_up(x, o);
        if (lane >= o) x += t;
    }
    __shared__ int wsum[4];
    if (lane == 63) wsum[wid] = x;
    __syncthreads();
    int woff = 0;
    for (int i = 0; i < wid; i++) woff += wsum[i];
    if (tid < nb) bsums[tid] = x + woff - v;        // exclusive
}

// (3) add block offsets; rowptr[N] = E (degrees sum to E analytically)
__global__ __launch_bounds__(SCAN_B) void add_offsets(int* __restrict__ rowptr,
                                                      const int* __restrict__ bsums) {
    int gid = blockIdx.x * SCAN_B + threadIdx.x;
    if (gid < N_) rowptr[gid] += bsums[blockIdx.x];
    if (gid == 0) rowptr[N_] = E_;
}

__global__ void fill_csr(const int* __restrict__ src, const int* __restrict__ dst,
                         const int* __restrict__ rowptr, int* __restrict__ cur,
                         int* __restrict__ col) {
    int i = blockIdx.x * blockDim.x + threadIdx.x;
    if (i < E_) {
        int d = dst[i];
        int p = atomicAdd(&cur[d], 1);
        col[rowptr[d] + p] = src[i];
    }
}

// ---------------- GEMM + fused attention logits ----------------
// Hout[n,128] = A[n,128] @ W[128,128];  es[n]=h.a_s  ed[n]=h.a_d
__global__ __launch_bounds__(256) void gemm128_fused(const float* __restrict__ A,
                                                     const float* __restrict__ W,
                                                     const float* __restrict__ a_s,
                                                     const float* __restrict__ a_d,
                                                     float* __restrict__ Hout,
                                                     float* __restrict__ es,
                                                     float* __restrict__ ed, int nrows) {
    __shared__ float xt[128][32];  // transposed x tile: xt[k][r]
    int block_row = blockIdx.x * 32;
    int tid = threadIdx.x;
    {
        int r = tid >> 3;
        int k0 = (tid & 7) * 16;
        int grow = block_row + r;
        const float* srcp = A + (size_t)grow * 128 + k0;
#pragma unroll
        for (int q = 0; q < 4; q++) {
            float4 v = (grow < nrows) ? *(const float4*)(srcp + q * 4)
                                      : make_float4(0.f, 0.f, 0.f, 0.f);
            xt[k0 + q * 4 + 0][r] = v.x;
            xt[k0 + q * 4 + 1][r] = v.y;
            xt[k0 + q * 4 + 2][r] = v.z;
            xt[k0 + q * 4 + 3][r] = v.w;
        }
    }
    __syncthreads();
    int c0 = (tid & 31) * 4;
    int r0 = (tid >> 5) * 4;
    float acc[4][4] = {};
#pragma unroll 4
    for (int k = 0; k < 128; k++) {
        float4 xv = *(const float4*)&xt[k][r0];
        float4 wv = *(const float4*)(W + k * 128 + c0);
        acc[0][0] += xv.x * wv.x; acc[0][1] += xv.x * wv.y; acc[0][2] += xv.x * wv.z; acc[0][3] += xv.x * wv.w;
        acc[1][0] += xv.y * wv.x; acc[1][1] += xv.y * wv.y; acc[1][2] += xv.y * wv.z; acc[1][3] += xv.y * wv.w;
        acc[2][0] += xv.z * wv.x; acc[2][1] += xv.z * wv.y; acc[2][2] += xv.z * wv.z; acc[2][3] += xv.z * wv.w;
        acc[3][0] += xv.w * wv.x; acc[3][1] += xv.w * wv.y; acc[3][2] += xv.w * wv.z; acc[3][3] += xv.w * wv.w;
    }
#pragma unroll
    for (int r = 0; r < 4; r++) {
        int grow = block_row + r0 + r;
        if (grow < nrows) {
            *(float4*)(Hout + (size_t)grow * 128 + c0) =
                make_float4(acc[r][0], acc[r][1], acc[r][2], acc[r][3]);
        }
    }
    // fused es/ed: per-thread partial dot over its 4 cols, reduce across the
    // 32 lanes (tid&31) that share a row group (xor 16..1 stays in-half).
    float4 asv = *(const float4*)(a_s + c0);
    float4 adv = *(const float4*)(a_d + c0);
#pragma unroll
    for (int r = 0; r < 4; r++) {
        float s = acc[r][0] * asv.x + acc[r][1] * asv.y + acc[r][2] * asv.z + acc[r][3] * asv.w;
        float d = acc[r][0] * adv.x + acc[r][1] * adv.y + acc[r][2] * adv.z + acc[r][3] * adv.w;
#pragma unroll
        for (int o = 16; o; o >>= 1) {
            s += __shfl_xor(s, o);
            d += __shfl_xor(d, o);
        }
        int grow = block_row + r0 + r;
        if ((tid & 31) == 0 && grow < nrows) {
            es[grow] = s;
            ed[grow] = d;
        }
    }
}

// ---------------- edge-softmax + aggregate (one wave per dst node) ----------------
__global__ __launch_bounds__(256) void gat_aggregate(const float* __restrict__ h,
                                                     const float* __restrict__ es,
                                                     const float* __restrict__ ed,
                                                     const int* __restrict__ rowptr,
                                                     const int* __restrict__ col,
                                                     const float* __restrict__ bias,
                                                     float* __restrict__ hout) {
    int node = blockIdx.x * 4 + (threadIdx.x >> 6);
    int lane = threadIdx.x & 63;
    if (node >= N_) return;
    int beg = rowptr[node];
    int end = rowptr[node + 1];
    float edn = ed[node];
    float e_self = leaky(es[node] + edn);

    // pass 1: max (lane-parallel over edges)
    float m = e_self;
    for (int i = beg + lane; i < end; i += 64) m = fmaxf(m, leaky(es[col[i]] + edn));
#pragma unroll
    for (int o = 32; o; o >>= 1) m = fmaxf(m, __shfl_xor(m, o));

    // pass 2: denom
    float z = 0.f;
    for (int i = beg + lane; i < end; i += 64) z += expf(leaky(es[col[i]] + edn) - m);
#pragma unroll
    for (int o = 32; o; o >>= 1) z += __shfl_xor(z, o);
    z += expf(e_self - m);
    float inv = 1.0f / (z + 1e-16f);

    // pass 3: weighted aggregation (serial edges, lanes span 128 features)
    float w = expf(e_self - m);
    float a0 = w * h[(size_t)node * 128 + lane];
    float a1 = w * h[(size_t)node * 128 + 64 + lane];
    for (int i = beg; i < end; ++i) {
        int s = col[i];
        float wi = expf(leaky(es[s] + edn) - m);
        a0 += wi * h[(size_t)s * 128 + lane];
        a1 += wi * h[(size_t)s * 128 + 64 + lane];
    }
    hout[(size_t)node * 128 + lane]      = fmaxf(a0 * inv + bias[lane], 0.f);
    hout[(size_t)node * 128 + 64 + lane] = fmaxf(a1 * inv + bias[64 + lane], 0.f);
}

// ---------------- global max pool ----------------
__device__ __forceinline__ int lower_bound_batch(const int* __restrict__ batch, int val) {
    int lo = 0, hi = N_;
    while (lo < hi) {
        int mid = (lo + hi) >> 1;
        if (batch[mid] < val) lo = mid + 1;
        else hi = mid;
    }
    return lo;
}

__global__ __launch_bounds__(512) void pool_max(const float* __restrict__ h,
                                                const int* __restrict__ batch,
                                                float* __restrict__ gpool) {
    int g = blockIdx.x;
    int s = lower_bound_batch(batch, g);
    int e = lower_bound_batch(batch, g + 1);
    int f = threadIdx.x & 127;
    int rg = threadIdx.x >> 7;  // 4 row groups
    float m = 0.f;  // h is post-ReLU (>=0), segments non-empty
    for (int i = s + rg; i < e; i += 4) m = fmaxf(m, h[(size_t)i * 128 + f]);
    __shared__ float red[4][128];
    red[rg][f] = m;
    __syncthreads();
    if (rg == 0) {
        m = fmaxf(fmaxf(red[0][f], red[1][f]), fmaxf(red[2][f], red[3][f]));
        gpool[g * 128 + f] = m;
    }
}

// ---------------- MLP head + log_softmax ----------------
__global__ __launch_bounds__(128) void head(const float* __restrict__ gpool,
                                            const float* __restrict__ W1,
                                            const float* __restrict__ b1,
                                            const float* __restrict__ W2,
                                            const float* __restrict__ b2,
                                            float* __restrict__ out) {
    int g = blockIdx.x;
    int t = threadIdx.x;
    __shared__ float gs[128], gp[128], lg[C_], lse;
    gs[t] = gpool[g * 128 + t];
    __syncthreads();
    float acc = b1[t];
#pragma unroll 8
    for (int k = 0; k < 128; k++) acc += gs[k] * W1[k * 128 + t];
    gp[t] = fmaxf(acc, 0.f);
    __syncthreads();
    if (t < C_) {
        float a2 = b2[t];
#pragma unroll 8
        for (int k = 0; k < 128; k++) a2 += gp[k] * W2[k * C_ + t];
        lg[t] = a2;
    }
    __syncthreads();
    if (t == 0) {
        float mm = lg[0];
#pragma unroll
        for (int i = 1; i < C_; i++) mm = fmaxf(mm, lg[i]);
        float ss = 0.f;
#pragma unroll
        for (int i = 0; i < C_; i++) ss += expf(lg[i] - mm);
        lse = mm + logf(ss);
    }
    __syncthreads();
    if (t < C_) out[g * C_ + t] = lg[t] - lse;
}

// ---------------- launch ----------------
extern "C" void kernel_launch(void* const* d_in, const int* in_sizes, int n_in,
                              void* d_out, int out_size, void* d_ws, size_t ws_size,
                              hipStream_t stream) {
    const float* x     = (const float*)d_in[0];
    const int*   eidx  = (const int*)d_in[1];
    const int*   batch = (const int*)d_in[2];
    const float* Wc    = (const float*)d_in[3];
    const float* a_src = (const float*)d_in[4];
    const float* a_dst = (const float*)d_in[5];
    const float* bc    = (const float*)d_in[6];
    const float* W1    = (const float*)d_in[7];
    const float* b1    = (const float*)d_in[8];
    const float* W2    = (const float*)d_in[9];
    const float* b2    = (const float*)d_in[10];
    float* out = (float*)d_out;

    const int* srcs = eidx;        // edge_index[0]
    const int* dsts = eidx + E_;   // edge_index[1]

    // workspace layout
    float* hA    = (float*)d_ws;             // N*128
    float* hB    = hA + (size_t)N_ * 128;    // N*128
    float* es    = hB + (size_t)N_ * 128;    // N
    float* ed    = es + N_;                  // N
    float* gpool = ed + N_;                  // G*128
    int* rowptr  = (int*)(gpool + G_ * 128); // N+1
    int* cnt     = rowptr + N_ + 1;          // N
    int* bsums   = cnt + N_;                 // NBLK
    int* col     = bsums + NBLK;             // E

    // ---- CSR build (once; reused by all layers) ----
    zero_i32<<<(N_ + 1023) / 1024, 1024, 0, stream>>>(cnt, N_);
    count_deg<<<(E_ + 255) / 256, 256, 0, stream>>>(dsts, cnt);
    scan_block<<<NBLK, SCAN_B, 0, stream>>>(cnt, rowptr, bsums);
    scan_bsums<<<1, 256, 0, stream>>>(bsums, NBLK);
    add_offsets<<<NBLK, SCAN_B, 0, stream>>>(rowptr, bsums);
    zero_i32<<<(N_ + 1023) / 1024, 1024, 0, stream>>>(cnt, N_);
    fill_csr<<<(E_ + 255) / 256, 256, 0, stream>>>(srcs, dsts, rowptr, cnt, col);

    // ---- 3 GAT layers ----
    const float* h_in = x;
    for (int l = 0; l < L_; ++l) {
        const float* Wl = Wc + (size_t)l * H_ * H_;
        gemm128_fused<<<(N_ + 31) / 32, 256, 0, stream>>>(
            h_in, Wl, a_src + l * H_, a_dst + l * H_, hA, es, ed, N_);
        gat_aggregate<<<(N_ + 3) / 4, 256, 0, stream>>>(hA, es, ed, rowptr, col, bc + l * H_, hB);
        h_in = hB;
    }

    // ---- pool + head ----
    pool_max<<<G_, 512, 0, stream>>>(hB, batch, gpool);
    head<<<G_, 128, 0, stream>>>(gpool, W1, b1, W2, b2, out);
}

// Round 3
// 370.367 us; speedup vs baseline: 1.5613x; 1.2789x over previous
//
#include <hip/hip_runtime.h>
#include <math.h>

#define N_ 50000
#define E_ 640000
#define H_ 128
#define L_ 3
#define G_ 256
#define C_ 10
#define NEG_SLOPE 0.2f

#define SCAN_B 256
#define NBLK ((N_ + SCAN_B - 1) / SCAN_B)   // 196

__device__ __forceinline__ float leaky(float x) { return x > 0.f ? x : NEG_SLOPE * x; }

// ---------------- utility ----------------
__global__ void zero_i32(int* __restrict__ p, int n) {
    int i = blockIdx.x * blockDim.x + threadIdx.x;
    if (i < n) p[i] = 0;
}

// ---------------- CSR build ----------------
__global__ void count_deg(const int* __restrict__ dst, int* __restrict__ cnt) {
    int i = blockIdx.x * blockDim.x + threadIdx.x;
    if (i < E_) atomicAdd(&cnt[dst[i]], 1);
}

// two-level scan: (1) per-block wave-shuffle scan + block sums
__global__ __launch_bounds__(SCAN_B) void scan_block(const int* __restrict__ cnt,
                                                     int* __restrict__ rowptr,
                                                     int* __restrict__ bsums) {
    int tid = threadIdx.x;
    int gid = blockIdx.x * SCAN_B + tid;
    int v = (gid < N_) ? cnt[gid] : 0;
    int lane = tid & 63, wid = tid >> 6;
    int x = v;
#pragma unroll
    for (int o = 1; o < 64; o <<= 1) {
        int t = __shfl_up(x, o);
        if (lane >= o) x += t;
    }
    __shared__ int wsum[4];
    if (lane == 63) wsum[wid] = x;
    __syncthreads();
    int woff = 0;
    for (int i = 0; i < wid; i++) woff += wsum[i];
    int incl = x + woff;
    if (gid < N_) rowptr[gid] = incl - v;            // exclusive within block
    if (tid == SCAN_B - 1) bsums[blockIdx.x] = incl; // block total
}

// (2) scan the 196 block sums in-place -> exclusive offsets
__global__ __launch_bounds__(256) void scan_bsums(int* __restrict__ bsums, int nb) {
    int tid = threadIdx.x;
    int v = (tid < nb) ? bsums[tid] : 0;
    int lane = tid & 63, wid = tid >> 6;
    int x = v;
#pragma unroll
    for (int o = 1; o < 64; o <<= 1) {
        int t = __shfl_up(x, o);
        if (lane >= o) x += t;
    }
    __shared__ int wsum[4];
    if (lane == 63) wsum[wid] = x;
    __syncthreads();
    int woff = 0;
    for (int i = 0; i < wid; i++) woff += wsum[i];
    if (tid < nb) bsums[tid] = x + woff - v;         // exclusive
}

// (3) add block offsets; rowptr[N] = E (degrees sum to E analytically)
__global__ __launch_bounds__(SCAN_B) void add_offsets(int* __restrict__ rowptr,
                                                      const int* __restrict__ bsums) {
    int gid = blockIdx.x * SCAN_B + threadIdx.x;
    if (gid < N_) rowptr[gid] += bsums[blockIdx.x];
    if (gid == 0) rowptr[N_] = E_;
}

__global__ void fill_csr(const int* __restrict__ src, const int* __restrict__ dst,
                         const int* __restrict__ rowptr, int* __restrict__ cur,
                         int* __restrict__ col) {
    int i = blockIdx.x * blockDim.x + threadIdx.x;
    if (i < E_) {
        int d = dst[i];
        int p = atomicAdd(&cur[d], 1);
        col[rowptr[d] + p] = src[i];
    }
}

// ---------------- GEMM + fused attention logits ----------------
// Hout[n,128] = A[n,128] @ W[128,128];  es[n]=h.a_s  ed[n]=h.a_d
__global__ __launch_bounds__(256) void gemm128_fused(const float* __restrict__ A,
                                                     const float* __restrict__ W,
                                                     const float* __restrict__ a_s,
                                                     const float* __restrict__ a_d,
                                                     float* __restrict__ Hout,
                                                     float* __restrict__ es,
                                                     float* __restrict__ ed, int nrows) {
    __shared__ float xt[128][32];  // transposed x tile: xt[k][r]
    int block_row = blockIdx.x * 32;
    int tid = threadIdx.x;
    {
        int r = tid >> 3;
        int k0 = (tid & 7) * 16;
        int grow = block_row + r;
        const float* srcp = A + (size_t)grow * 128 + k0;
#pragma unroll
        for (int q = 0; q < 4; q++) {
            float4 v = (grow < nrows) ? *(const float4*)(srcp + q * 4)
                                      : make_float4(0.f, 0.f, 0.f, 0.f);
            xt[k0 + q * 4 + 0][r] = v.x;
            xt[k0 + q * 4 + 1][r] = v.y;
            xt[k0 + q * 4 + 2][r] = v.z;
            xt[k0 + q * 4 + 3][r] = v.w;
        }
    }
    __syncthreads();
    int c0 = (tid & 31) * 4;
    int r0 = (tid >> 5) * 4;
    float acc[4][4] = {};
#pragma unroll 4
    for (int k = 0; k < 128; k++) {
        float4 xv = *(const float4*)&xt[k][r0];
        float4 wv = *(const float4*)(W + k * 128 + c0);
        acc[0][0] += xv.x * wv.x; acc[0][1] += xv.x * wv.y; acc[0][2] += xv.x * wv.z; acc[0][3] += xv.x * wv.w;
        acc[1][0] += xv.y * wv.x; acc[1][1] += xv.y * wv.y; acc[1][2] += xv.y * wv.z; acc[1][3] += xv.y * wv.w;
        acc[2][0] += xv.z * wv.x; acc[2][1] += xv.z * wv.y; acc[2][2] += xv.z * wv.z; acc[2][3] += xv.z * wv.w;
        acc[3][0] += xv.w * wv.x; acc[3][1] += xv.w * wv.y; acc[3][2] += xv.w * wv.z; acc[3][3] += xv.w * wv.w;
    }
#pragma unroll
    for (int r = 0; r < 4; r++) {
        int grow = block_row + r0 + r;
        if (grow < nrows) {
            *(float4*)(Hout + (size_t)grow * 128 + c0) =
                make_float4(acc[r][0], acc[r][1], acc[r][2], acc[r][3]);
        }
    }
    // fused es/ed: per-thread partial dot over its 4 cols, reduce across the
    // 32 lanes (tid&31) that share a row group (xor 16..1 stays in-half).
    float4 asv = *(const float4*)(a_s + c0);
    float4 adv = *(const float4*)(a_d + c0);
#pragma unroll
    for (int r = 0; r < 4; r++) {
        float s = acc[r][0] * asv.x + acc[r][1] * asv.y + acc[r][2] * asv.z + acc[r][3] * asv.w;
        float d = acc[r][0] * adv.x + acc[r][1] * adv.y + acc[r][2] * adv.z + acc[r][3] * adv.w;
#pragma unroll
        for (int o = 16; o; o >>= 1) {
            s += __shfl_xor(s, o);
            d += __shfl_xor(d, o);
        }
        int grow = block_row + r0 + r;
        if ((tid & 31) == 0 && grow < nrows) {
            es[grow] = s;
            ed[grow] = d;
        }
    }
}

// ---------------- edge-softmax + aggregate (one wave per dst node) ----------------
// chunk-0 edge data cached in registers; per-edge weights staged in LDS;
// h gathered as float2 (lane covers features 2*lane, 2*lane+1).
__global__ __launch_bounds__(256) void gat_aggregate(const float* __restrict__ h,
                                                     const float* __restrict__ es,
                                                     const float* __restrict__ ed,
                                                     const int* __restrict__ rowptr,
                                                     const int* __restrict__ col,
                                                     const float* __restrict__ bias,
                                                     float* __restrict__ hout) {
    __shared__ int   lds_s[4][64];
    __shared__ float lds_w[4][64];
    int wv = threadIdx.x >> 6;
    int lane = threadIdx.x & 63;
    int node = blockIdx.x * 4 + wv;
    if (node >= N_) return;
    int beg = rowptr[node];
    int end = rowptr[node + 1];
    float edn = ed[node];
    float e_self = leaky(es[node] + edn);

    // chunk-0: one edge per lane, cached in registers
    int i0 = beg + lane;
    int c0 = 0;
    float e0 = -INFINITY;
    if (i0 < end) { c0 = col[i0]; e0 = leaky(es[c0] + edn); }

    // max over all edges + self
    float m = e0;
    for (int i = i0 + 64; i < end; i += 64) m = fmaxf(m, leaky(es[col[i]] + edn));
#pragma unroll
    for (int o = 32; o; o >>= 1) m = fmaxf(m, __shfl_xor(m, o));
    m = fmaxf(m, e_self);

    // denom; chunk-0 weights from registers
    float w0 = (i0 < end) ? expf(e0 - m) : 0.f;
    float z = w0;
    for (int i = i0 + 64; i < end; i += 64) z += expf(leaky(es[col[i]] + edn) - m);
#pragma unroll
    for (int o = 32; o; o >>= 1) z += __shfl_xor(z, o);
    float w_self = expf(e_self - m);
    z += w_self;
    float inv = 1.0f / (z + 1e-16f);

    // aggregation: LDS-broadcast weights, float2 h gather
    const float2* __restrict__ h2 = (const float2*)h;
    float2 acc;
    {
        float2 hv = h2[(size_t)node * 64 + lane];
        acc.x = w_self * hv.x;
        acc.y = w_self * hv.y;
    }
    lds_s[wv][lane] = c0;
    lds_w[wv][lane] = w0;
    int nl = min(end - beg, 64);
#pragma unroll 4
    for (int j = 0; j < nl; ++j) {
        int s = lds_s[wv][j];
        float wj = lds_w[wv][j];
        float2 hv = h2[(size_t)s * 64 + lane];
        acc.x += wj * hv.x;
        acc.y += wj * hv.y;
    }
    // rare: degree > 64
    for (int cb = beg + 64; cb < end; cb += 64) {
        int idx = cb + lane;
        int cs = 0; float cw = 0.f;
        if (idx < end) { cs = col[idx]; cw = expf(leaky(es[cs] + edn) - m); }
        lds_s[wv][lane] = cs;
        lds_w[wv][lane] = cw;
        int n2 = min(end - cb, 64);
        for (int j = 0; j < n2; ++j) {
            int s = lds_s[wv][j];
            float wj = lds_w[wv][j];
            float2 hv = h2[(size_t)s * 64 + lane];
            acc.x += wj * hv.x;
            acc.y += wj * hv.y;
        }
    }

    float2 bv = ((const float2*)bias)[lane];
    float2 o;
    o.x = fmaxf(acc.x * inv + bv.x, 0.f);
    o.y = fmaxf(acc.y * inv + bv.y, 0.f);
    ((float2*)hout)[(size_t)node * 64 + lane] = o;
}

// ---------------- global max pool ----------------
__device__ __forceinline__ int lower_bound_batch(const int* __restrict__ batch, int val) {
    int lo = 0, hi = N_;
    while (lo < hi) {
        int mid = (lo + hi) >> 1;
        if (batch[mid] < val) lo = mid + 1;
        else hi = mid;
    }
    return lo;
}

__global__ __launch_bounds__(512) void pool_max(const float* __restrict__ h,
                                                const int* __restrict__ batch,
                                                float* __restrict__ gpool) {
    int g = blockIdx.x;
    int s = lower_bound_batch(batch, g);
    int e = lower_bound_batch(batch, g + 1);
    int f = threadIdx.x & 127;
    int rg = threadIdx.x >> 7;  // 4 row groups
    float m = 0.f;  // h is post-ReLU (>=0), segments non-empty
    for (int i = s + rg; i < e; i += 4) m = fmaxf(m, h[(size_t)i * 128 + f]);
    __shared__ float red[4][128];
    red[rg][f] = m;
    __syncthreads();
    if (rg == 0) {
        m = fmaxf(fmaxf(red[0][f], red[1][f]), fmaxf(red[2][f], red[3][f]));
        gpool[g * 128 + f] = m;
    }
}

// ---------------- MLP head + log_softmax ----------------
__global__ __launch_bounds__(128) void head(const float* __restrict__ gpool,
                                            const float* __restrict__ W1,
                                            const float* __restrict__ b1,
                                            const float* __restrict__ W2,
                                            const float* __restrict__ b2,
                                            float* __restrict__ out) {
    int g = blockIdx.x;
    int t = threadIdx.x;
    __shared__ float gs[128], gp[128], lg[C_], lse;
    gs[t] = gpool[g * 128 + t];
    __syncthreads();
    float acc = b1[t];
#pragma unroll 8
    for (int k = 0; k < 128; k++) acc += gs[k] * W1[k * 128 + t];
    gp[t] = fmaxf(acc, 0.f);
    __syncthreads();
    if (t < C_) {
        float a2 = b2[t];
#pragma unroll 8
        for (int k = 0; k < 128; k++) a2 += gp[k] * W2[k * C_ + t];
        lg[t] = a2;
    }
    __syncthreads();
    if (t == 0) {
        float mm = lg[0];
#pragma unroll
        for (int i = 1; i < C_; i++) mm = fmaxf(mm, lg[i]);
        float ss = 0.f;
#pragma unroll
        for (int i = 0; i < C_; i++) ss += expf(lg[i] - mm);
        lse = mm + logf(ss);
    }
    __syncthreads();
    if (t < C_) out[g * C_ + t] = lg[t] - lse;
}

// ---------------- launch ----------------
extern "C" void kernel_launch(void* const* d_in, const int* in_sizes, int n_in,
                              void* d_out, int out_size, void* d_ws, size_t ws_size,
                              hipStream_t stream) {
    const float* x     = (const float*)d_in[0];
    const int*   eidx  = (const int*)d_in[1];
    const int*   batch = (const int*)d_in[2];
    const float* Wc    = (const float*)d_in[3];
    const float* a_src = (const float*)d_in[4];
    const float* a_dst = (const float*)d_in[5];
    const float* bc    = (const float*)d_in[6];
    const float* W1    = (const float*)d_in[7];
    const float* b1    = (const float*)d_in[8];
    const float* W2    = (const float*)d_in[9];
    const float* b2    = (const float*)d_in[10];
    float* out = (float*)d_out;

    const int* srcs = eidx;        // edge_index[0]
    const int* dsts = eidx + E_;   // edge_index[1]

    // workspace layout
    float* hA    = (float*)d_ws;             // N*128
    float* hB    = hA + (size_t)N_ * 128;    // N*128
    float* es    = hB + (size_t)N_ * 128;    // N
    float* ed    = es + N_;                  // N
    float* gpool = ed + N_;                  // G*128
    int* rowptr  = (int*)(gpool + G_ * 128); // N+1
    int* cnt     = rowptr + N_ + 1;          // N
    int* bsums   = cnt + N_;                 // NBLK
    int* col     = bsums + NBLK;             // E

    // ---- CSR build (once; reused by all layers) ----
    zero_i32<<<(N_ + 1023) / 1024, 1024, 0, stream>>>(cnt, N_);
    count_deg<<<(E_ + 255) / 256, 256, 0, stream>>>(dsts, cnt);
    scan_block<<<NBLK, SCAN_B, 0, stream>>>(cnt, rowptr, bsums);
    scan_bsums<<<1, 256, 0, stream>>>(bsums, NBLK);
    add_offsets<<<NBLK, SCAN_B, 0, stream>>>(rowptr, bsums);
    zero_i32<<<(N_ + 1023) / 1024, 1024, 0, stream>>>(cnt, N_);
    fill_csr<<<(E_ + 255) / 256, 256, 0, stream>>>(srcs, dsts, rowptr, cnt, col);

    // ---- 3 GAT layers ----
    const float* h_in = x;
    for (int l = 0; l < L_; ++l) {
        const float* Wl = Wc + (size_t)l * H_ * H_;
        gemm128_fused<<<(N_ + 31) / 32, 256, 0, stream>>>(
            h_in, Wl, a_src + l * H_, a_dst + l * H_, hA, es, ed, N_);
        gat_aggregate<<<(N_ + 3) / 4, 256, 0, stream>>>(hA, es, ed, rowptr, col, bc + l * H_, hB);
        h_in = hB;
    }

    // ---- pool + head ----
    pool_max<<<G_, 512, 0, stream>>>(hB, batch, gpool);
    head<<<G_, 128, 0, stream>>>(gpool, W1, b1, W2, b2, out);
}

// Round 4
// 321.097 us; speedup vs baseline: 1.8009x; 1.1534x over previous
//
#include <hip/hip_runtime.h>
#include <hip/hip_fp16.h>
#include <math.h>

#define N_ 50000
#define E_ 640000
#define H_ 128
#define L_ 3
#define G_ 256
#define C_ 10
#define NEG_SLOPE 0.2f

#define SCAN_B 256
#define NBLK ((N_ + SCAN_B - 1) / SCAN_B)   // 196

__device__ __forceinline__ float leaky(float x) { return x > 0.f ? x : NEG_SLOPE * x; }

// ---------------- utility ----------------
__global__ void zero_i32(int* __restrict__ p, int n) {
    int i = blockIdx.x * blockDim.x + threadIdx.x;
    if (i < n) p[i] = 0;
}

// ---------------- CSR build ----------------
__global__ void count_deg(const int* __restrict__ dst, int* __restrict__ cnt) {
    int i = blockIdx.x * blockDim.x + threadIdx.x;
    if (i < E_) atomicAdd(&cnt[dst[i]], 1);
}

// two-level scan: (1) per-block wave-shuffle scan + block sums
__global__ __launch_bounds__(SCAN_B) void scan_block(const int* __restrict__ cnt,
                                                     int* __restrict__ rowptr,
                                                     int* __restrict__ bsums) {
    int tid = threadIdx.x;
    int gid = blockIdx.x * SCAN_B + tid;
    int v = (gid < N_) ? cnt[gid] : 0;
    int lane = tid & 63, wid = tid >> 6;
    int x = v;
#pragma unroll
    for (int o = 1; o < 64; o <<= 1) {
        int t = __shfl_up(x, o);
        if (lane >= o) x += t;
    }
    __shared__ int wsum[4];
    if (lane == 63) wsum[wid] = x;
    __syncthreads();
    int woff = 0;
    for (int i = 0; i < wid; i++) woff += wsum[i];
    int incl = x + woff;
    if (gid < N_) rowptr[gid] = incl - v;            // exclusive within block
    if (tid == SCAN_B - 1) bsums[blockIdx.x] = incl; // block total
}

// (2) scan the 196 block sums in-place -> exclusive offsets
__global__ __launch_bounds__(256) void scan_bsums(int* __restrict__ bsums, int nb) {
    int tid = threadIdx.x;
    int v = (tid < nb) ? bsums[tid] : 0;
    int lane = tid & 63, wid = tid >> 6;
    int x = v;
#pragma unroll
    for (int o = 1; o < 64; o <<= 1) {
        int t = __shfl_up(x, o);
        if (lane >= o) x += t;
    }
    __shared__ int wsum[4];
    if (lane == 63) wsum[wid] = x;
    __syncthreads();
    int woff = 0;
    for (int i = 0; i < wid; i++) woff += wsum[i];
    if (tid < nb) bsums[tid] = x + woff - v;         // exclusive
}

// (3) add block offsets; rowptr[N] = E (degrees sum to E analytically)
__global__ __launch_bounds__(SCAN_B) void add_offsets(int* __restrict__ rowptr,
                                                      const int* __restrict__ bsums) {
    int gid = blockIdx.x * SCAN_B + threadIdx.x;
    if (gid < N_) rowptr[gid] += bsums[blockIdx.x];
    if (gid == 0) rowptr[N_] = E_;
}

__global__ void fill_csr(const int* __restrict__ src, const int* __restrict__ dst,
                         const int* __restrict__ rowptr, int* __restrict__ cur,
                         int* __restrict__ col) {
    int i = blockIdx.x * blockDim.x + threadIdx.x;
    if (i < E_) {
        int d = dst[i];
        int p = atomicAdd(&cur[d], 1);
        col[rowptr[d] + p] = src[i];
    }
}

// ---------------- GEMM + fused attention logits, fp16 h output ----------------
// h16[n,128] = fp16(A[n,128] @ W[128,128]);  es[n]=h.a_s  ed[n]=h.a_d (fp32)
__global__ __launch_bounds__(256) void gemm128_fused(const float* __restrict__ A,
                                                     const float* __restrict__ W,
                                                     const float* __restrict__ a_s,
                                                     const float* __restrict__ a_d,
                                                     __half* __restrict__ h16,
                                                     float* __restrict__ es,
                                                     float* __restrict__ ed, int nrows) {
    __shared__ float xt[128][32];  // transposed x tile: xt[k][r]
    int block_row = blockIdx.x * 32;
    int tid = threadIdx.x;
    {
        int r = tid >> 3;
        int k0 = (tid & 7) * 16;
        int grow = block_row + r;
        const float* srcp = A + (size_t)grow * 128 + k0;
#pragma unroll
        for (int q = 0; q < 4; q++) {
            float4 v = (grow < nrows) ? *(const float4*)(srcp + q * 4)
                                      : make_float4(0.f, 0.f, 0.f, 0.f);
            xt[k0 + q * 4 + 0][r] = v.x;
            xt[k0 + q * 4 + 1][r] = v.y;
            xt[k0 + q * 4 + 2][r] = v.z;
            xt[k0 + q * 4 + 3][r] = v.w;
        }
    }
    __syncthreads();
    int c0 = (tid & 31) * 4;
    int r0 = (tid >> 5) * 4;
    float acc[4][4] = {};
#pragma unroll 4
    for (int k = 0; k < 128; k++) {
        float4 xv = *(const float4*)&xt[k][r0];
        float4 wv = *(const float4*)(W + k * 128 + c0);
        acc[0][0] += xv.x * wv.x; acc[0][1] += xv.x * wv.y; acc[0][2] += xv.x * wv.z; acc[0][3] += xv.x * wv.w;
        acc[1][0] += xv.y * wv.x; acc[1][1] += xv.y * wv.y; acc[1][2] += xv.y * wv.z; acc[1][3] += xv.y * wv.w;
        acc[2][0] += xv.z * wv.x; acc[2][1] += xv.z * wv.y; acc[2][2] += xv.z * wv.z; acc[2][3] += xv.z * wv.w;
        acc[3][0] += xv.w * wv.x; acc[3][1] += xv.w * wv.y; acc[3][2] += xv.w * wv.z; acc[3][3] += xv.w * wv.w;
    }
#pragma unroll
    for (int r = 0; r < 4; r++) {
        int grow = block_row + r0 + r;
        if (grow < nrows) {
            union { __half2 h2[2]; float2 f2; } u;
            u.h2[0] = __floats2half2_rn(acc[r][0], acc[r][1]);
            u.h2[1] = __floats2half2_rn(acc[r][2], acc[r][3]);
            *(float2*)(h16 + (size_t)grow * 128 + c0) = u.f2;
        }
    }
    // fused es/ed: per-thread partial dot over its 4 cols, reduce across the
    // 32 lanes (tid&31) that share a row group.
    float4 asv = *(const float4*)(a_s + c0);
    float4 adv = *(const float4*)(a_d + c0);
#pragma unroll
    for (int r = 0; r < 4; r++) {
        float s = acc[r][0] * asv.x + acc[r][1] * asv.y + acc[r][2] * asv.z + acc[r][3] * asv.w;
        float d = acc[r][0] * adv.x + acc[r][1] * adv.y + acc[r][2] * adv.z + acc[r][3] * adv.w;
#pragma unroll
        for (int o = 16; o; o >>= 1) {
            s += __shfl_xor(s, o);
            d += __shfl_xor(d, o);
        }
        int grow = block_row + r0 + r;
        if ((tid & 31) == 0 && grow < nrows) {
            es[grow] = s;
            ed[grow] = d;
        }
    }
}

// ---------------- edge-softmax + aggregate (one wave per dst node) ----------------
// chunk-0 edge data cached in registers; per-edge weights staged in LDS;
// h gathered as half2 (lane covers features 2*lane, 2*lane+1), accum fp32.
__global__ __launch_bounds__(256) void gat_aggregate(const __half* __restrict__ h16,
                                                     const float* __restrict__ es,
                                                     const float* __restrict__ ed,
                                                     const int* __restrict__ rowptr,
                                                     const int* __restrict__ col,
                                                     const float* __restrict__ bias,
                                                     float* __restrict__ hout) {
    __shared__ int   lds_s[4][64];
    __shared__ float lds_w[4][64];
    int wv = threadIdx.x >> 6;
    int lane = threadIdx.x & 63;
    int node = blockIdx.x * 4 + wv;
    if (node >= N_) return;
    int beg = rowptr[node];
    int end = rowptr[node + 1];
    float edn = ed[node];
    float e_self = leaky(es[node] + edn);

    // chunk-0: one edge per lane, cached in registers
    int i0 = beg + lane;
    int c0 = 0;
    float e0 = -INFINITY;
    if (i0 < end) { c0 = col[i0]; e0 = leaky(es[c0] + edn); }

    // max over all edges + self
    float m = e0;
    for (int i = i0 + 64; i < end; i += 64) m = fmaxf(m, leaky(es[col[i]] + edn));
#pragma unroll
    for (int o = 32; o; o >>= 1) m = fmaxf(m, __shfl_xor(m, o));
    m = fmaxf(m, e_self);

    // denom; chunk-0 weights from registers
    float w0 = (i0 < end) ? expf(e0 - m) : 0.f;
    float z = w0;
    for (int i = i0 + 64; i < end; i += 64) z += expf(leaky(es[col[i]] + edn) - m);
#pragma unroll
    for (int o = 32; o; o >>= 1) z += __shfl_xor(z, o);
    float w_self = expf(e_self - m);
    z += w_self;
    float inv = 1.0f / (z + 1e-16f);

    // aggregation: LDS-broadcast weights, half2 h gather
    const __half2* __restrict__ h2 = (const __half2*)h16;
    float2 acc;
    {
        float2 hv = __half22float2(h2[(size_t)node * 64 + lane]);
        acc.x = w_self * hv.x;
        acc.y = w_self * hv.y;
    }
    lds_s[wv][lane] = c0;
    lds_w[wv][lane] = w0;
    int nl = min(end - beg, 64);
#pragma unroll 4
    for (int j = 0; j < nl; ++j) {
        int s = lds_s[wv][j];
        float wj = lds_w[wv][j];
        float2 hv = __half22float2(h2[(size_t)s * 64 + lane]);
        acc.x += wj * hv.x;
        acc.y += wj * hv.y;
    }
    // rare: degree > 64
    for (int cb = beg + 64; cb < end; cb += 64) {
        int idx = cb + lane;
        int cs = 0; float cw = 0.f;
        if (idx < end) { cs = col[idx]; cw = expf(leaky(es[cs] + edn) - m); }
        lds_s[wv][lane] = cs;
        lds_w[wv][lane] = cw;
        int n2 = min(end - cb, 64);
        for (int j = 0; j < n2; ++j) {
            int s = lds_s[wv][j];
            float wj = lds_w[wv][j];
            float2 hv = __half22float2(h2[(size_t)s * 64 + lane]);
            acc.x += wj * hv.x;
            acc.y += wj * hv.y;
        }
    }

    float2 bv = ((const float2*)bias)[lane];
    float2 o;
    o.x = fmaxf(acc.x * inv + bv.x, 0.f);
    o.y = fmaxf(acc.y * inv + bv.y, 0.f);
    ((float2*)hout)[(size_t)node * 64 + lane] = o;
}

// ---------------- global max pool ----------------
__device__ __forceinline__ int lower_bound_batch(const int* __restrict__ batch, int val) {
    int lo = 0, hi = N_;
    while (lo < hi) {
        int mid = (lo + hi) >> 1;
        if (batch[mid] < val) lo = mid + 1;
        else hi = mid;
    }
    return lo;
}

__global__ __launch_bounds__(512) void pool_max(const float* __restrict__ h,
                                                const int* __restrict__ batch,
                                                float* __restrict__ gpool) {
    int g = blockIdx.x;
    int s = lower_bound_batch(batch, g);
    int e = lower_bound_batch(batch, g + 1);
    int f = threadIdx.x & 127;
    int rg = threadIdx.x >> 7;  // 4 row groups
    float m = 0.f;  // h is post-ReLU (>=0), segments non-empty
    for (int i = s + rg; i < e; i += 4) m = fmaxf(m, h[(size_t)i * 128 + f]);
    __shared__ float red[4][128];
    red[rg][f] = m;
    __syncthreads();
    if (rg == 0) {
        m = fmaxf(fmaxf(red[0][f], red[1][f]), fmaxf(red[2][f], red[3][f]));
        gpool[g * 128 + f] = m;
    }
}

// ---------------- MLP head + log_softmax ----------------
__global__ __launch_bounds__(128) void head(const float* __restrict__ gpool,
                                            const float* __restrict__ W1,
                                            const float* __restrict__ b1,
                                            const float* __restrict__ W2,
                                            const float* __restrict__ b2,
                                            float* __restrict__ out) {
    int g = blockIdx.x;
    int t = threadIdx.x;
    __shared__ float gs[128], gp[128], lg[C_], lse;
    gs[t] = gpool[g * 128 + t];
    __syncthreads();
    float acc = b1[t];
#pragma unroll 8
    for (int k = 0; k < 128; k++) acc += gs[k] * W1[k * 128 + t];
    gp[t] = fmaxf(acc, 0.f);
    __syncthreads();
    if (t < C_) {
        float a2 = b2[t];
#pragma unroll 8
        for (int k = 0; k < 128; k++) a2 += gp[k] * W2[k * C_ + t];
        lg[t] = a2;
    }
    __syncthreads();
    if (t == 0) {
        float mm = lg[0];
#pragma unroll
        for (int i = 1; i < C_; i++) mm = fmaxf(mm, lg[i]);
        float ss = 0.f;
#pragma unroll
        for (int i = 0; i < C_; i++) ss += expf(lg[i] - mm);
        lse = mm + logf(ss);
    }
    __syncthreads();
    if (t < C_) out[g * C_ + t] = lg[t] - lse;
}

// ---------------- launch ----------------
extern "C" void kernel_launch(void* const* d_in, const int* in_sizes, int n_in,
                              void* d_out, int out_size, void* d_ws, size_t ws_size,
                              hipStream_t stream) {
    const float* x     = (const float*)d_in[0];
    const int*   eidx  = (const int*)d_in[1];
    const int*   batch = (const int*)d_in[2];
    const float* Wc    = (const float*)d_in[3];
    const float* a_src = (const float*)d_in[4];
    const float* a_dst = (const float*)d_in[5];
    const float* bc    = (const float*)d_in[6];
    const float* W1    = (const float*)d_in[7];
    const float* b1    = (const float*)d_in[8];
    const float* W2    = (const float*)d_in[9];
    const float* b2    = (const float*)d_in[10];
    float* out = (float*)d_out;

    const int* srcs = eidx;        // edge_index[0]
    const int* dsts = eidx + E_;   // edge_index[1]

    // workspace layout
    float* hA    = (float*)d_ws;             // N*128 floats (fp16 copy lives here)
    float* hB    = hA + (size_t)N_ * 128;    // N*128
    float* es    = hB + (size_t)N_ * 128;    // N
    float* ed    = es + N_;                  // N
    float* gpool = ed + N_;                  // G*128
    int* rowptr  = (int*)(gpool + G_ * 128); // N+1
    int* cnt     = rowptr + N_ + 1;          // N
    int* bsums   = cnt + N_;                 // NBLK
    int* col     = bsums + NBLK;             // E
    __half* h16  = (__half*)hA;              // N*128 halves (within hA's extent)

    // ---- CSR build (once; reused by all layers) ----
    zero_i32<<<(N_ + 1023) / 1024, 1024, 0, stream>>>(cnt, N_);
    count_deg<<<(E_ + 255) / 256, 256, 0, stream>>>(dsts, cnt);
    scan_block<<<NBLK, SCAN_B, 0, stream>>>(cnt, rowptr, bsums);
    scan_bsums<<<1, 256, 0, stream>>>(bsums, NBLK);
    add_offsets<<<NBLK, SCAN_B, 0, stream>>>(rowptr, bsums);
    zero_i32<<<(N_ + 1023) / 1024, 1024, 0, stream>>>(cnt, N_);
    fill_csr<<<(E_ + 255) / 256, 256, 0, stream>>>(srcs, dsts, rowptr, cnt, col);

    // ---- 3 GAT layers ----
    const float* h_in = x;
    for (int l = 0; l < L_; ++l) {
        const float* Wl = Wc + (size_t)l * H_ * H_;
        gemm128_fused<<<(N_ + 31) / 32, 256, 0, stream>>>(
            h_in, Wl, a_src + l * H_, a_dst + l * H_, h16, es, ed, N_);
        gat_aggregate<<<(N_ + 3) / 4, 256, 0, stream>>>(h16, es, ed, rowptr, col, bc + l * H_, hB);
        h_in = hB;
    }

    // ---- pool + head ----
    pool_max<<<G_, 512, 0, stream>>>(hB, batch, gpool);
    head<<<G_, 128, 0, stream>>>(gpool, W1, b1, W2, b2, out);
}

// Round 5
// 261.506 us; speedup vs baseline: 2.2112x; 1.2279x over previous
//
#include <hip/hip_runtime.h>
#include <hip/hip_fp16.h>
#include <math.h>

#define N_ 50000
#define E_ 640000
#define H_ 128
#define L_ 3
#define G_ 256
#define C_ 10
#define NEG_SLOPE 0.2f

#define SCAN_B 256
#define NBLK ((N_ + SCAN_B - 1) / SCAN_B)   // 196

typedef _Float16 half8 __attribute__((ext_vector_type(8)));
typedef float f32x4 __attribute__((ext_vector_type(4)));

__device__ __forceinline__ float leaky(float x) { return x > 0.f ? x : NEG_SLOPE * x; }

// ---------------- utility ----------------
__global__ void zero_i32(int* __restrict__ p, int n) {
    int i = blockIdx.x * blockDim.x + threadIdx.x;
    if (i < n) p[i] = 0;
}

// ---------------- CSR build ----------------
__global__ void count_deg(const int* __restrict__ dst, int* __restrict__ cnt) {
    int i = blockIdx.x * blockDim.x + threadIdx.x;
    if (i < E_) atomicAdd(&cnt[dst[i]], 1);
}

__global__ __launch_bounds__(SCAN_B) void scan_block(const int* __restrict__ cnt,
                                                     int* __restrict__ rowptr,
                                                     int* __restrict__ bsums) {
    int tid = threadIdx.x;
    int gid = blockIdx.x * SCAN_B + tid;
    int v = (gid < N_) ? cnt[gid] : 0;
    int lane = tid & 63, wid = tid >> 6;
    int x = v;
#pragma unroll
    for (int o = 1; o < 64; o <<= 1) {
        int t = __shfl_up(x, o);
        if (lane >= o) x += t;
    }
    __shared__ int wsum[4];
    if (lane == 63) wsum[wid] = x;
    __syncthreads();
    int woff = 0;
    for (int i = 0; i < wid; i++) woff += wsum[i];
    int incl = x + woff;
    if (gid < N_) rowptr[gid] = incl - v;            // exclusive within block
    if (tid == SCAN_B - 1) bsums[blockIdx.x] = incl; // block total
}

__global__ __launch_bounds__(256) void scan_bsums(int* __restrict__ bsums, int nb) {
    int tid = threadIdx.x;
    int v = (tid < nb) ? bsums[tid] : 0;
    int lane = tid & 63, wid = tid >> 6;
    int x = v;
#pragma unroll
    for (int o = 1; o < 64; o <<= 1) {
        int t = __shfl_up(x, o);
        if (lane >= o) x += t;
    }
    __shared__ int wsum[4];
    if (lane == 63) wsum[wid] = x;
    __syncthreads();
    int woff = 0;
    for (int i = 0; i < wid; i++) woff += wsum[i];
    if (tid < nb) bsums[tid] = x + woff - v;         // exclusive
}

__global__ __launch_bounds__(SCAN_B) void add_offsets(int* __restrict__ rowptr,
                                                      const int* __restrict__ bsums) {
    int gid = blockIdx.x * SCAN_B + threadIdx.x;
    if (gid < N_) rowptr[gid] += bsums[blockIdx.x];
    if (gid == 0) rowptr[N_] = E_;
}

__global__ void fill_csr(const int* __restrict__ src, const int* __restrict__ dst,
                         const int* __restrict__ rowptr, int* __restrict__ cur,
                         int* __restrict__ col) {
    int i = blockIdx.x * blockDim.x + threadIdx.x;
    if (i < E_) {
        int d = dst[i];
        int p = atomicAdd(&cur[d], 1);
        col[rowptr[d] + p] = src[i];
    }
}

// ---------------- weight prep: Wt[l][144][128] fp16 ----------------
// rows 0..127: W^T (Wt[n][k] = W[k][n]); row 128: W@a_src; row 129: W@a_dst;
// rows 130..143: zero padding (so GEMM n-tile 8 yields es/ed in cols 128/129).
__global__ __launch_bounds__(256) void prep_weights(const float* __restrict__ Wc,
                                                    const float* __restrict__ a_src,
                                                    const float* __restrict__ a_dst,
                                                    __half* __restrict__ Wt) {
    int l = blockIdx.x;
    const float* W = Wc + l * 16384;
    __half* T = Wt + (size_t)l * 144 * 128;
    int t = threadIdx.x;
    for (int e = t; e < 16384; e += 256) {
        int k = e >> 7, n = e & 127;          // read W linearly (coalesced)
        T[n * 128 + k] = __float2half(W[e]);  // scattered 2B writes, L2-absorbed
    }
    if (t < 128) {
        int k = t;
        const float* as = a_src + l * 128;
        const float* ad = a_dst + l * 128;
        float s = 0.f, d = 0.f;
#pragma unroll 8
        for (int n = 0; n < 128; n++) {
            float w = W[k * 128 + n];
            s += w * as[n];
            d += w * ad[n];
        }
        T[128 * 128 + k] = __float2half(s);
        T[129 * 128 + k] = __float2half(d);
    } else {
        int kk = t - 128;
        for (int r = 130; r < 144; r++) T[r * 128 + kk] = __float2half(0.f);
    }
}

// ---------------- MFMA GEMM: h16 = fp16(A @ W), es/ed fused ----------------
// block = 256 threads (4 waves), BM=64 rows, N=128(+16 pad) cols, K=128.
// LDS tiles XOR-swizzled (byte ^= (row&7)<<4) for conflict-free ds_read_b128.
__global__ __launch_bounds__(256) void gemm_mfma(const float* __restrict__ A,
                                                 const __half* __restrict__ Wt,
                                                 __half* __restrict__ h16,
                                                 float* __restrict__ es,
                                                 float* __restrict__ ed) {
    __shared__ __half Asw[64 * 128];    // 16 KB
    __shared__ __half Bsw[144 * 128];   // 36 KB
    int tid = threadIdx.x;
    int brow = blockIdx.x * 64;

    // --- stage A: fp32 -> fp16, swizzled ---
    {
        int r = tid >> 2;             // 0..63
        int kc = (tid & 3) * 32;      // float index
        int grow = brow + r;
        float v[32];
        if (grow < N_) {
            const float4* p = (const float4*)(A + (size_t)grow * 128 + kc);
#pragma unroll
            for (int q = 0; q < 8; q++) {
                float4 f = p[q];
                v[q * 4] = f.x; v[q * 4 + 1] = f.y; v[q * 4 + 2] = f.z; v[q * 4 + 3] = f.w;
            }
        } else {
#pragma unroll
            for (int q = 0; q < 32; q++) v[q] = 0.f;
        }
#pragma unroll
        for (int q = 0; q < 4; q++) {
            half8 h;
#pragma unroll
            for (int j = 0; j < 8; j++) h[j] = (_Float16)v[q * 8 + j];
            int kbyte = kc * 2 + q * 16;
            int addr = r * 256 + (kbyte ^ ((r & 7) << 4));
            *(half8*)((char*)Asw + addr) = h;
        }
    }
    // --- stage B: linear fp16 copy, swizzled (2304 16B chunks) ---
    {
        const float4* src = (const float4*)Wt;
#pragma unroll
        for (int i = 0; i < 9; i++) {
            int c = tid + i * 256;
            int o = c * 16;
            int n = o >> 8;
            float4 val = src[c];
            int addr = n * 256 + ((o & 255) ^ ((n & 7) << 4));
            *(float4*)((char*)Bsw + addr) = val;
        }
    }
    __syncthreads();

    // --- MFMA: wave w handles rows w*16..w*16+15, 9 n-tiles, 4 k-steps ---
    int w = tid >> 6, l = tid & 63;
    int lrow = l & 15, lk = l >> 4;
    f32x4 acc[9];
#pragma unroll
    for (int t = 0; t < 9; t++) acc[t] = (f32x4)0.f;
#pragma unroll
    for (int kk = 0; kk < 4; kk++) {
        int kbyte = kk * 64 + lk * 16;
        int arow = w * 16 + lrow;
        half8 af = *(const half8*)((const char*)Asw + arow * 256 + (kbyte ^ ((arow & 7) << 4)));
#pragma unroll
        for (int t = 0; t < 9; t++) {
            int n = t * 16 + lrow;
            half8 bf = *(const half8*)((const char*)Bsw + n * 256 + (kbyte ^ ((n & 7) << 4)));
            acc[t] = __builtin_amdgcn_mfma_f32_16x16x32_f16(af, bf, acc[t], 0, 0, 0);
        }
    }

    // --- epilogue: C[row][col], row=(lk*4+reg), col=lrow+16t (m89 layout) ---
    int row0 = brow + w * 16 + lk * 4;
#pragma unroll
    for (int r = 0; r < 4; r++) {
        int grow = row0 + r;
        if (grow < N_) {
            __half* dst = h16 + (size_t)grow * 128 + lrow;
#pragma unroll
            for (int t = 0; t < 8; t++) dst[t * 16] = __float2half(acc[t][r]);
            if (lrow == 0) es[grow] = acc[8][r];
            else if (lrow == 1) ed[grow] = acc[8][r];
        }
    }
}

// ---------------- edge-softmax + aggregate (one wave per dst node) ----------------
__global__ __launch_bounds__(256) void gat_aggregate(const __half* __restrict__ h16,
                                                     const float* __restrict__ es,
                                                     const float* __restrict__ ed,
                                                     const int* __restrict__ rowptr,
                                                     const int* __restrict__ col,
                                                     const float* __restrict__ bias,
                                                     float* __restrict__ hout) {
    __shared__ int   lds_s[4][64];
    __shared__ float lds_w[4][64];
    int wv = threadIdx.x >> 6;
    int lane = threadIdx.x & 63;
    int node = blockIdx.x * 4 + wv;
    if (node >= N_) return;
    int beg = rowptr[node];
    int end = rowptr[node + 1];
    float edn = ed[node];
    float e_self = leaky(es[node] + edn);

    int i0 = beg + lane;
    int c0 = 0;
    float e0 = -INFINITY;
    if (i0 < end) { c0 = col[i0]; e0 = leaky(es[c0] + edn); }

    float m = e0;
    for (int i = i0 + 64; i < end; i += 64) m = fmaxf(m, leaky(es[col[i]] + edn));
#pragma unroll
    for (int o = 32; o; o >>= 1) m = fmaxf(m, __shfl_xor(m, o));
    m = fmaxf(m, e_self);

    float w0 = (i0 < end) ? expf(e0 - m) : 0.f;
    float z = w0;
    for (int i = i0 + 64; i < end; i += 64) z += expf(leaky(es[col[i]] + edn) - m);
#pragma unroll
    for (int o = 32; o; o >>= 1) z += __shfl_xor(z, o);
    float w_self = expf(e_self - m);
    z += w_self;
    float inv = 1.0f / (z + 1e-16f);

    const __half2* __restrict__ h2 = (const __half2*)h16;
    float2 acc;
    {
        float2 hv = __half22float2(h2[(size_t)node * 64 + lane]);
        acc.x = w_self * hv.x;
        acc.y = w_self * hv.y;
    }
    lds_s[wv][lane] = c0;
    lds_w[wv][lane] = w0;
    int nl = min(end - beg, 64);
#pragma unroll 4
    for (int j = 0; j < nl; ++j) {
        int s = lds_s[wv][j];
        float wj = lds_w[wv][j];
        float2 hv = __half22float2(h2[(size_t)s * 64 + lane]);
        acc.x += wj * hv.x;
        acc.y += wj * hv.y;
    }
    for (int cb = beg + 64; cb < end; cb += 64) {
        int idx = cb + lane;
        int cs = 0; float cw = 0.f;
        if (idx < end) { cs = col[idx]; cw = expf(leaky(es[cs] + edn) - m); }
        lds_s[wv][lane] = cs;
        lds_w[wv][lane] = cw;
        int n2 = min(end - cb, 64);
        for (int j = 0; j < n2; ++j) {
            int s = lds_s[wv][j];
            float wj = lds_w[wv][j];
            float2 hv = __half22float2(h2[(size_t)s * 64 + lane]);
            acc.x += wj * hv.x;
            acc.y += wj * hv.y;
        }
    }

    float2 bv = ((const float2*)bias)[lane];
    float2 o;
    o.x = fmaxf(acc.x * inv + bv.x, 0.f);
    o.y = fmaxf(acc.y * inv + bv.y, 0.f);
    ((float2*)hout)[(size_t)node * 64 + lane] = o;
}

// ---------------- global max pool ----------------
__device__ __forceinline__ int lower_bound_batch(const int* __restrict__ batch, int val) {
    int lo = 0, hi = N_;
    while (lo < hi) {
        int mid = (lo + hi) >> 1;
        if (batch[mid] < val) lo = mid + 1;
        else hi = mid;
    }
    return lo;
}

__global__ __launch_bounds__(512) void pool_max(const float* __restrict__ h,
                                                const int* __restrict__ batch,
                                                float* __restrict__ gpool) {
    int g = blockIdx.x;
    int s = lower_bound_batch(batch, g);
    int e = lower_bound_batch(batch, g + 1);
    int f = threadIdx.x & 127;
    int rg = threadIdx.x >> 7;
    float m = 0.f;  // h is post-ReLU (>=0), segments non-empty
    for (int i = s + rg; i < e; i += 4) m = fmaxf(m, h[(size_t)i * 128 + f]);
    __shared__ float red[4][128];
    red[rg][f] = m;
    __syncthreads();
    if (rg == 0) {
        m = fmaxf(fmaxf(red[0][f], red[1][f]), fmaxf(red[2][f], red[3][f]));
        gpool[g * 128 + f] = m;
    }
}

// ---------------- MLP head + log_softmax ----------------
__global__ __launch_bounds__(128) void head(const float* __restrict__ gpool,
                                            const float* __restrict__ W1,
                                            const float* __restrict__ b1,
                                            const float* __restrict__ W2,
                                            const float* __restrict__ b2,
                                            float* __restrict__ out) {
    int g = blockIdx.x;
    int t = threadIdx.x;
    __shared__ float gs[128], gp[128], lg[C_], lse;
    gs[t] = gpool[g * 128 + t];
    __syncthreads();
    float acc = b1[t];
#pragma unroll 8
    for (int k = 0; k < 128; k++) acc += gs[k] * W1[k * 128 + t];
    gp[t] = fmaxf(acc, 0.f);
    __syncthreads();
    if (t < C_) {
        float a2 = b2[t];
#pragma unroll 8
        for (int k = 0; k < 128; k++) a2 += gp[k] * W2[k * C_ + t];
        lg[t] = a2;
    }
    __syncthreads();
    if (t == 0) {
        float mm = lg[0];
#pragma unroll
        for (int i = 1; i < C_; i++) mm = fmaxf(mm, lg[i]);
        float ss = 0.f;
#pragma unroll
        for (int i = 0; i < C_; i++) ss += expf(lg[i] - mm);
        lse = mm + logf(ss);
    }
    __syncthreads();
    if (t < C_) out[g * C_ + t] = lg[t] - lse;
}

// ---------------- launch ----------------
extern "C" void kernel_launch(void* const* d_in, const int* in_sizes, int n_in,
                              void* d_out, int out_size, void* d_ws, size_t ws_size,
                              hipStream_t stream) {
    const float* x     = (const float*)d_in[0];
    const int*   eidx  = (const int*)d_in[1];
    const int*   batch = (const int*)d_in[2];
    const float* Wc    = (const float*)d_in[3];
    const float* a_src = (const float*)d_in[4];
    const float* a_dst = (const float*)d_in[5];
    const float* bc    = (const float*)d_in[6];
    const float* W1    = (const float*)d_in[7];
    const float* b1    = (const float*)d_in[8];
    const float* W2    = (const float*)d_in[9];
    const float* b2    = (const float*)d_in[10];
    float* out = (float*)d_out;

    const int* srcs = eidx;        // edge_index[0]
    const int* dsts = eidx + E_;   // edge_index[1]

    // workspace layout (all 16B-aligned up to col)
    float*  hA    = (float*)d_ws;              // N*128 floats (h16 lives here)
    float*  hB    = hA + (size_t)N_ * 128;     // N*128
    float*  es    = hB + (size_t)N_ * 128;     // N
    float*  ed    = es + N_;                   // N
    float*  gpool = ed + N_;                   // G*128
    __half* Wt    = (__half*)(gpool + G_ * 128); // 3*144*128 halves
    int*    rowptr = (int*)(Wt + (size_t)3 * 144 * 128); // N+1
    int*    cnt   = rowptr + N_ + 1;           // N
    int*    bsums = cnt + N_;                  // NBLK
    int*    col   = bsums + NBLK;              // E
    __half* h16   = (__half*)hA;               // N*128 halves

    // ---- weight prep + CSR build (CSR reused by all layers) ----
    prep_weights<<<L_, 256, 0, stream>>>(Wc, a_src, a_dst, Wt);
    zero_i32<<<(N_ + 1023) / 1024, 1024, 0, stream>>>(cnt, N_);
    count_deg<<<(E_ + 255) / 256, 256, 0, stream>>>(dsts, cnt);
    scan_block<<<NBLK, SCAN_B, 0, stream>>>(cnt, rowptr, bsums);
    scan_bsums<<<1, 256, 0, stream>>>(bsums, NBLK);
    add_offsets<<<NBLK, SCAN_B, 0, stream>>>(rowptr, bsums);
    zero_i32<<<(N_ + 1023) / 1024, 1024, 0, stream>>>(cnt, N_);
    fill_csr<<<(E_ + 255) / 256, 256, 0, stream>>>(srcs, dsts, rowptr, cnt, col);

    // ---- 3 GAT layers ----
    const float* h_in = x;
    for (int l = 0; l < L_; ++l) {
        gemm_mfma<<<(N_ + 63) / 64, 256, 0, stream>>>(
            h_in, Wt + (size_t)l * 144 * 128, h16, es, ed);
        gat_aggregate<<<(N_ + 3) / 4, 256, 0, stream>>>(h16, es, ed, rowptr, col, bc + l * H_, hB);
        h_in = hB;
    }

    // ---- pool + head ----
    pool_max<<<G_, 512, 0, stream>>>(hB, batch, gpool);
    head<<<G_, 128, 0, stream>>>(gpool, W1, b1, W2, b2, out);
}